// Round 12
// baseline (146.709 us; speedup 1.0000x reference)
//
#include <hip/hip_runtime.h>
#include <hip/hip_bf16.h>

#define DI __device__ __forceinline__

typedef __attribute__((ext_vector_type(8))) __bf16 bf16x8;
typedef __attribute__((ext_vector_type(4))) float f32x4;
typedef __attribute__((ext_vector_type(8))) short short8;
typedef __attribute__((ext_vector_type(4))) short short4v;
typedef unsigned short u16;

static constexpr int BB = 4, SS = 2048, EE = 1024, AA = 1024;

DI float bf2f(u16 u) { unsigned v = ((unsigned)u) << 16; float f; __builtin_memcpy(&f, &v, 4); return f; }
DI u16 f2bf(float f) { __hip_bfloat16 h = __float2bfloat16(f); u16 u; __builtin_memcpy(&u, &h, 2); return u; }

DI void gload16(const void* g, void* l) {
  __builtin_amdgcn_global_load_lds((const __attribute__((address_space(1))) void*)g,
                                   (__attribute__((address_space(3))) void*)l, 16, 0, 0);
}

// bijective XCD swizzle: nwg % 8 == 0.
DI int xcd_swz(int lin, int nwg) {
  int cpx = nwg >> 3;
  return (lin & 7) * cpx + (lin >> 3);
}

// LDS tile rows are 128B (64 bf16). Physical 16B chunk = logical ^ (row&7).
DI bf16x8 read_frag(const char* lds, int R, int c) {
  return *(const bf16x8*)(lds + R * 128 + ((c ^ (R & 7)) << 4));
}

// ================= 128x128 GEMM core: T3-min double-buffered, 64KB -> 2 blocks/CU ==========
// Key lesson (r9/r10): 2 blocks/CU co-residency (foreign waves fill barrier stalls) beats
// every 1-block/CU software pipeline tried in r3-r9 (680-755 TF there; this class ~805+).
DI void stage_tile(const u16* g, int ld, char* lds, int wid, int lane) {
#pragma unroll
  for (int i = 0; i < 4; ++i) {
    int blk = i * 4 + wid;
    int r = blk * 8 + (lane >> 3);
    int c = (lane & 7) ^ (r & 7);
    gload16((const char*)(g + (size_t)r * ld) + c * 16, lds + blk * 1024);
  }
}

DI void gemm_tile(const u16* Ap, int lda, const u16* Bp, int ldb, int ksteps,
                  char* smem, f32x4 acc[4][4]) {
  const int tid = threadIdx.x, lane = tid & 63, wid = tid >> 6;
  const int wr = wid >> 1, wc = wid & 1;
  stage_tile(Ap, lda, smem, wid, lane);
  stage_tile(Bp, ldb, smem + 16384, wid, lane);
  asm volatile("s_waitcnt vmcnt(0)" ::: "memory");
  __syncthreads();
#pragma unroll 1
  for (int ks = 0; ks < ksteps; ++ks) {
    const char* As = smem + (ks & 1) * 32768;
    const char* Bs = As + 16384;
    char* nxt = smem + ((ks & 1) ^ 1) * 32768;
    if (ks + 1 < ksteps) {
      stage_tile(Ap + (size_t)(ks + 1) * 64, lda, nxt, wid, lane);
      stage_tile(Bp + (size_t)(ks + 1) * 64, ldb, nxt + 16384, wid, lane);
    }
#pragma unroll
    for (int ksub = 0; ksub < 2; ++ksub) {
      const int c = ksub * 4 + (lane >> 4);
      bf16x8 af[4], bfr[4];
#pragma unroll
      for (int mi = 0; mi < 4; ++mi) af[mi] = read_frag(As, wr * 64 + mi * 16 + (lane & 15), c);
#pragma unroll
      for (int ni = 0; ni < 4; ++ni) bfr[ni] = read_frag(Bs, wc * 64 + ni * 16 + (lane & 15), c);
#pragma unroll
      for (int mi = 0; mi < 4; ++mi)
#pragma unroll
        for (int ni = 0; ni < 4; ++ni)
          acc[mi][ni] = __builtin_amdgcn_mfma_f32_16x16x32_bf16(af[mi], bfr[ni], acc[mi][ni], 0, 0, 0);
    }
    if (ks + 1 < ksteps) asm volatile("s_waitcnt vmcnt(0)" ::: "memory");
    __syncthreads();
  }
}

// ================= proj: C[8192][3072] = Xb @ Wt^T via 128^2 tiles, persistent x3 ==========
// 512 blocks (2/CU, 1 dispatch round); each block does 3 tiles: fixed mt, nt = nb+{0,8,16}.
// A-panel stays hot in L2 across the 3 tiles; per-XCD working set ~4MB.
__global__ __launch_bounds__(256) void k_proj9(const u16* __restrict__ Xb, const u16* __restrict__ Wt,
                                               u16* __restrict__ Qb, u16* __restrict__ Vt) {
  __shared__ __align__(16) char smem[65536];
  const int lin = blockIdx.x;            // 512; lin&7 = XCD
  const int x = lin & 7;
  const int jj = lin >> 3;               // [0,64)
  const int mt = x * 8 + (jj & 7);       // [0,64): 8 m-tiles per XCD
  const int nb = jj >> 3;                // [0,8)
  const u16* Ap = Xb + (size_t)mt * 128 * EE;
  const int lane = threadIdx.x & 63, wid = threadIdx.x >> 6;
  const int lane15 = lane & 15, lhi = lane >> 4;
  const int wr = wid >> 1, wc = wid & 1;

#pragma unroll 1
  for (int t3 = 0; t3 < 3; ++t3) {
    const int nt = nb + t3 * 8;          // [0,24)
    const u16* Bp = Wt + (size_t)nt * 128 * EE;
    f32x4 acc[4][4];
#pragma unroll
    for (int p = 0; p < 4; ++p)
#pragma unroll
      for (int q = 0; q < 4; ++q) acc[p][q] = (f32x4)0.f;
    gemm_tile(Ap, EE, Bp, EE, EE / 64, smem, acc);

    const int r0 = mt * 128 + wr * 64;
    const int c0 = nt * 128 + wc * 64;
    if (nt < 16) {                       // Q (nt<8) or K (8<=nt<16), row-major
      u16* base = Qb + (size_t)(nt >> 3) * ((size_t)BB * SS * AA);
      const int cc = c0 & 1023;
#pragma unroll
      for (int mi = 0; mi < 4; ++mi)
#pragma unroll
        for (int ni = 0; ni < 4; ++ni)
#pragma unroll
          for (int r = 0; r < 4; ++r) {
            int row = r0 + mi * 16 + lhi * 4 + r;
            base[(size_t)row * AA + cc + ni * 16 + lane15] = f2bf(acc[mi][ni][r]);
          }
    } else {                             // V: write transposed to Vt[b][a][s]
#pragma unroll
      for (int mi = 0; mi < 4; ++mi) {
        const int grow = r0 + mi * 16 + lhi * 4;   // 4 consecutive s-rows
        const int b = grow >> 11, s = grow & 2047;
#pragma unroll
        for (int ni = 0; ni < 4; ++ni) {
          const int a = c0 - 2048 + ni * 16 + lane15;
          short4v o;
#pragma unroll
          for (int r = 0; r < 4; ++r) o[r] = (short)f2bf(acc[mi][ni][r]);
          *(short4v*)(Vt + (size_t)b * AA * SS + (size_t)a * SS + s) = o;
        }
      }
    }
  }
}

// ---------- prep: cast X -> bf16 (32B/thread), cast+transpose W -> Wt, zero rowsum ----------
__global__ __launch_bounds__(256) void k_prep(const float* __restrict__ X, const float* __restrict__ Wq,
                                              const float* __restrict__ Wk, const float* __restrict__ Wv,
                                              u16* __restrict__ Xb, u16* __restrict__ Wt,
                                              float* __restrict__ rowsum) {
  __shared__ float t[64][65];
  const int bid = blockIdx.x;
  if (bid < 4096) {
    if (bid < 32) rowsum[bid * 256 + threadIdx.x] = 0.f;
    size_t i = ((size_t)bid * 256 + threadIdx.x) * 8;
    f32x4 f0 = *(const f32x4*)(X + i);
    f32x4 f1 = *(const f32x4*)(X + i + 4);
    short8 o;
#pragma unroll
    for (int j = 0; j < 4; ++j) { o[j] = (short)f2bf(f0[j]); o[4 + j] = (short)f2bf(f1[j]); }
    *(short8*)(Xb + i) = o;
  } else {
    const int bx = bid - 4096;                 // [0,768)
    const int w = bx >> 8, rem = bx & 255;
    const int k0 = (rem & 15) * 64, n0 = (rem >> 4) * 64;
    const float* W = (w == 0) ? Wq : ((w == 1) ? Wk : Wv);
    u16* Wo = Wt + (size_t)w * EE * AA;
    const int tx = threadIdx.x & 63, ty = threadIdx.x >> 6;
#pragma unroll
    for (int r = 0; r < 16; ++r) {
      int k = r * 4 + ty;
      t[k][tx] = W[(size_t)(k0 + k) * AA + n0 + tx];
    }
    __syncthreads();
#pragma unroll
    for (int r = 0; r < 16; ++r) {
      int n = r * 4 + ty;
      Wo[(size_t)(n0 + n) * EE + k0 + tx] = f2bf(t[tx][n]);
    }
  }
}

// ---------- P = exp(Q @ K^T / 32) causal, + rowsum (LDS-combined, 128 atomics/block) ----------
__global__ __launch_bounds__(256) void k_scores(const u16* __restrict__ Q, const u16* __restrict__ K,
                                                u16* __restrict__ Sc, float* __restrict__ rowsum) {
  __shared__ __align__(16) char smem[65536];
  __shared__ float rsh[128];
  const int wg = xcd_swz(blockIdx.x, 544);
  const int b = wg / 136, t = wg % 136;
  int i = (int)((sqrtf(8.f * t + 1.f) - 1.f) * 0.5f);
  while ((i + 1) * (i + 2) / 2 <= t) ++i;
  while (i * (i + 1) / 2 > t) --i;
  const int j = t - i * (i + 1) / 2;
  const u16* Ap = Q + (size_t)b * SS * AA + (size_t)i * 128 * AA;
  const u16* Bp = K + (size_t)b * SS * AA + (size_t)j * 128 * AA;
  u16* Op = Sc + (size_t)b * SS * SS;
  float* rs = rowsum + (size_t)b * SS;
  f32x4 acc[4][4];
#pragma unroll
  for (int p = 0; p < 4; ++p)
#pragma unroll
    for (int q = 0; q < 4; ++q) acc[p][q] = (f32x4)0.f;
  if (threadIdx.x < 128) rsh[threadIdx.x] = 0.f;
  gemm_tile(Ap, AA, Bp, AA, AA / 64, smem, acc);   // ends with __syncthreads -> rsh visible
  const int lane = threadIdx.x & 63, wid = threadIdx.x >> 6;
  const int r0 = i * 128 + (wid >> 1) * 64, c0 = j * 128 + (wid & 1) * 64;
#pragma unroll
  for (int mi = 0; mi < 4; ++mi)
#pragma unroll
    for (int r = 0; r < 4; ++r) {
      const int row = r0 + mi * 16 + ((lane >> 4) << 2) + r;
      float psum = 0.f;
#pragma unroll
      for (int ni = 0; ni < 4; ++ni) {
        const int col = c0 + ni * 16 + (lane & 15);
        float e = (col <= row) ? __expf(acc[mi][ni][r] * 0.03125f) : 0.f;
        psum += e;
        Op[(size_t)row * SS + col] = f2bf(e);
      }
      psum += __shfl_xor(psum, 1, 16);
      psum += __shfl_xor(psum, 2, 16);
      psum += __shfl_xor(psum, 4, 16);
      psum += __shfl_xor(psum, 8, 16);
      if ((lane & 15) == 0) atomicAdd(&rsh[row - i * 128], psum);
    }
  __syncthreads();
  if (threadIdx.x < 128) atomicAdd(&rs[i * 128 + threadIdx.x], rsh[threadIdx.x]);
}

// ---------- out = (P @ Vt^T) / rowsum (causal K-loop), fp32 out ----------
// Co-residency pairing (r11): CU c hosts lin=c and lin=c+256 -> i pair {x, 15-x}, 17 units/CU.
__global__ __launch_bounds__(256) void k_pv(const u16* __restrict__ Sc, const u16* __restrict__ Vt,
                                            const float* __restrict__ rowsum, float* __restrict__ Out) {
  __shared__ __align__(16) char smem[65536];
  const int lin = blockIdx.x;          // 512; lin&7 = XCD
  const int x = lin & 7;
  const int half = (lin >> 8) & 1;     // co-resident partner has half^1
  const int rest = (lin >> 3) & 31;    // [0,32): b*8 + nt
  const int b = rest >> 3, nt = rest & 7;
  const int i = half ? (15 - x) : x;
  const u16* Ap = Sc + (size_t)b * SS * SS + (size_t)i * 128 * SS;
  const u16* Bp = Vt + (size_t)b * AA * SS + (size_t)nt * 128 * SS;
  const float* rs = rowsum + (size_t)b * SS;
  float* Op = Out + (size_t)b * SS * AA;
  const int lane = threadIdx.x & 63, wid = threadIdx.x >> 6;
  const int r0 = i * 128 + (wid >> 1) * 64, c0 = nt * 128 + (wid & 1) * 64;
  // hoist rowsum loads above the GEMM (ready since k_scores; latency hides under staging)
  float rsv[4][4];
#pragma unroll
  for (int mi = 0; mi < 4; ++mi)
#pragma unroll
    for (int r = 0; r < 4; ++r)
      rsv[mi][r] = rs[r0 + mi * 16 + ((lane >> 4) << 2) + r];
  f32x4 acc[4][4];
#pragma unroll
  for (int p = 0; p < 4; ++p)
#pragma unroll
    for (int q = 0; q < 4; ++q) acc[p][q] = (f32x4)0.f;
  gemm_tile(Ap, SS, Bp, SS, 2 * (i + 1), smem, acc);
#pragma unroll
  for (int mi = 0; mi < 4; ++mi)
#pragma unroll
    for (int r = 0; r < 4; ++r) {
      const int row = r0 + mi * 16 + ((lane >> 4) << 2) + r;
      const float inv = 1.f / rsv[mi][r];
#pragma unroll
      for (int ni = 0; ni < 4; ++ni) {
        const int col = c0 + ni * 16 + (lane & 15);
        Op[(size_t)row * AA + col] = acc[mi][ni][r] * inv;
      }
    }
}

extern "C" void kernel_launch(void* const* d_in, const int* in_sizes, int n_in,
                              void* d_out, int out_size, void* d_ws, size_t ws_size,
                              hipStream_t stream) {
  const float* X  = (const float*)d_in[0];
  const float* Wq = (const float*)d_in[1];
  const float* Wk = (const float*)d_in[2];
  const float* Wv = (const float*)d_in[3];
  float* Out = (float*)d_out;
  char* ws = (char*)d_ws;
  u16* Xb = (u16*)ws;                              // 16 MiB: [8192][1024]
  u16* Wt = (u16*)(ws + (16u << 20));              // 6 MiB: [3072][1024] (n-major, Q|K|V)
  u16* Qb = (u16*)(ws + (22u << 20));              // 16 MiB  } Qb, Kb contiguous (16MiB apart)
  u16* Kb = (u16*)(ws + (38u << 20));              // 16 MiB  }
  u16* Vt = (u16*)(ws + (70u << 20));              // 16 MiB: per-batch [1024][2048]
  u16* Sc = (u16*)(ws + (86u << 20));              // 32 MiB: [4][2048][2048]
  float* rowsum = (float*)(ws + (118u << 20));     // 32 KiB: [4][2048]

  k_prep<<<dim3(4096 + 768), 256, 0, stream>>>(X, Wq, Wk, Wv, Xb, Wt, rowsum);
  k_proj9<<<dim3(512), 256, 0, stream>>>(Xb, Wt, Qb, Vt);
  k_scores<<<dim3(136 * BB), 256, 0, stream>>>(Qb, Kb, Sc, rowsum);
  k_pv<<<dim3(512), 256, 0, stream>>>(Sc, Vt, rowsum, Out);
}

// Round 13
// 145.424 us; speedup vs baseline: 1.0088x; 1.0088x over previous
//
#include <hip/hip_runtime.h>
#include <hip/hip_bf16.h>

#define DI __device__ __forceinline__

typedef __attribute__((ext_vector_type(8))) __bf16 bf16x8;
typedef __attribute__((ext_vector_type(4))) float f32x4;
typedef __attribute__((ext_vector_type(8))) short short8;
typedef __attribute__((ext_vector_type(4))) short short4v;
typedef unsigned short u16;

static constexpr int BB = 4, SS = 2048, EE = 1024, AA = 1024;

DI float bf2f(u16 u) { unsigned v = ((unsigned)u) << 16; float f; __builtin_memcpy(&f, &v, 4); return f; }
DI u16 f2bf(float f) { __hip_bfloat16 h = __float2bfloat16(f); u16 u; __builtin_memcpy(&u, &h, 2); return u; }

DI void gload16(const void* g, void* l) {
  __builtin_amdgcn_global_load_lds((const __attribute__((address_space(1))) void*)g,
                                   (__attribute__((address_space(3))) void*)l, 16, 0, 0);
}

// bijective XCD swizzle: nwg % 8 == 0.
DI int xcd_swz(int lin, int nwg) {
  int cpx = nwg >> 3;
  return (lin & 7) * cpx + (lin >> 3);
}

// LDS tile rows are 128B (64 bf16). Physical 16B chunk = logical ^ (row&7).
DI bf16x8 read_frag(const char* lds, int R, int c) {
  return *(const bf16x8*)(lds + R * 128 + ((c ^ (R & 7)) << 4));
}

// ================= 128x128 GEMM core: T3-min double-buffered, 64KB -> 2 blocks/CU ==========
// Key lesson (r9/r10): 2 blocks/CU co-residency (foreign waves fill barrier stalls) beats
// every 1-block/CU software pipeline tried in r3-r9 (680-755 TF there; this class ~805+).
DI void stage_tile(const u16* g, int ld, char* lds, int wid, int lane) {
#pragma unroll
  for (int i = 0; i < 4; ++i) {
    int blk = i * 4 + wid;
    int r = blk * 8 + (lane >> 3);
    int c = (lane & 7) ^ (r & 7);
    gload16((const char*)(g + (size_t)r * ld) + c * 16, lds + blk * 1024);
  }
}

DI void gemm_tile(const u16* Ap, int lda, const u16* Bp, int ldb, int ksteps,
                  char* smem, f32x4 acc[4][4]) {
  const int tid = threadIdx.x, lane = tid & 63, wid = tid >> 6;
  const int wr = wid >> 1, wc = wid & 1;
  stage_tile(Ap, lda, smem, wid, lane);
  stage_tile(Bp, ldb, smem + 16384, wid, lane);
  asm volatile("s_waitcnt vmcnt(0)" ::: "memory");
  __syncthreads();
#pragma unroll 1
  for (int ks = 0; ks < ksteps; ++ks) {
    const char* As = smem + (ks & 1) * 32768;
    const char* Bs = As + 16384;
    char* nxt = smem + ((ks & 1) ^ 1) * 32768;
    if (ks + 1 < ksteps) {
      stage_tile(Ap + (size_t)(ks + 1) * 64, lda, nxt, wid, lane);
      stage_tile(Bp + (size_t)(ks + 1) * 64, ldb, nxt + 16384, wid, lane);
    }
#pragma unroll
    for (int ksub = 0; ksub < 2; ++ksub) {
      const int c = ksub * 4 + (lane >> 4);
      bf16x8 af[4], bfr[4];
#pragma unroll
      for (int mi = 0; mi < 4; ++mi) af[mi] = read_frag(As, wr * 64 + mi * 16 + (lane & 15), c);
#pragma unroll
      for (int ni = 0; ni < 4; ++ni) bfr[ni] = read_frag(Bs, wc * 64 + ni * 16 + (lane & 15), c);
#pragma unroll
      for (int mi = 0; mi < 4; ++mi)
#pragma unroll
        for (int ni = 0; ni < 4; ++ni)
          acc[mi][ni] = __builtin_amdgcn_mfma_f32_16x16x32_bf16(af[mi], bfr[ni], acc[mi][ni], 0, 0, 0);
    }
    if (ks + 1 < ksteps) asm volatile("s_waitcnt vmcnt(0)" ::: "memory");
    __syncthreads();
  }
}

// ================= proj: C[8192][3072] = Xb @ Wt^T via 128^2 tiles =================
// r11 champion: 1536 wgs = 3 exact rounds at 2 blocks/CU. Per-XCD: 8 m-tiles x (12+12) n,
// m-fastest -> L2 working set ~3.3MB < 4MB. Tile wholly Q, K, or V; V written transposed.
__global__ __launch_bounds__(256) void k_proj8(const u16* __restrict__ Xb, const u16* __restrict__ Wt,
                                               u16* __restrict__ Qb, u16* __restrict__ Vt) {
  __shared__ __align__(16) char smem[65536];
  const int lin = blockIdx.x;            // 1536; lin&7 = XCD
  const int x = lin & 7;
  const int jj = lin >> 3;               // [0,192)
  const int nh = jj / 96, rem = jj - nh * 96;
  const int nt = nh * 12 + (rem >> 3);   // [0,24)
  const int mt = x * 8 + (rem & 7);      // [0,64): 8 m-tiles per XCD
  const u16* Ap = Xb + (size_t)mt * 128 * EE;
  const u16* Bp = Wt + (size_t)nt * 128 * EE;
  f32x4 acc[4][4];
#pragma unroll
  for (int p = 0; p < 4; ++p)
#pragma unroll
    for (int q = 0; q < 4; ++q) acc[p][q] = (f32x4)0.f;
  gemm_tile(Ap, EE, Bp, EE, EE / 64, smem, acc);

  const int lane = threadIdx.x & 63, wid = threadIdx.x >> 6;
  const int lane15 = lane & 15, lhi = lane >> 4;
  const int wr = wid >> 1, wc = wid & 1;
  const int r0 = mt * 128 + wr * 64;
  const int c0 = nt * 128 + wc * 64;
  if (nt < 16) {                         // Q (nt<8) or K (8<=nt<16), row-major
    u16* base = Qb + (size_t)(nt >> 3) * ((size_t)BB * SS * AA);
    const int cc = c0 & 1023;
#pragma unroll
    for (int mi = 0; mi < 4; ++mi)
#pragma unroll
      for (int ni = 0; ni < 4; ++ni)
#pragma unroll
        for (int r = 0; r < 4; ++r) {
          int row = r0 + mi * 16 + lhi * 4 + r;
          base[(size_t)row * AA + cc + ni * 16 + lane15] = f2bf(acc[mi][ni][r]);
        }
  } else {                               // V: write transposed to Vt[b][a][s]
#pragma unroll
    for (int mi = 0; mi < 4; ++mi) {
      const int grow = r0 + mi * 16 + lhi * 4;   // 4 consecutive s-rows
      const int b = grow >> 11, s = grow & 2047;
#pragma unroll
      for (int ni = 0; ni < 4; ++ni) {
        const int a = c0 - 2048 + ni * 16 + lane15;
        short4v o;
#pragma unroll
        for (int r = 0; r < 4; ++r) o[r] = (short)f2bf(acc[mi][ni][r]);
        *(short4v*)(Vt + (size_t)b * AA * SS + (size_t)a * SS + s) = o;
      }
    }
  }
}

// ---------- prep (r11 version): cast X -> bf16 (16B/thread), W transpose, zero rowsum ----------
__global__ __launch_bounds__(256) void k_prep(const float* __restrict__ X, const float* __restrict__ Wq,
                                              const float* __restrict__ Wk, const float* __restrict__ Wv,
                                              u16* __restrict__ Xb, u16* __restrict__ Wt,
                                              float* __restrict__ rowsum) {
  __shared__ float t[64][65];
  const int bid = blockIdx.x;
  if (bid < 8192) {
    if (bid < 32) rowsum[bid * 256 + threadIdx.x] = 0.f;
    size_t i = ((size_t)bid * 256 + threadIdx.x) * 4;
    f32x4 f = *(const f32x4*)(X + i);
    short4v o;
#pragma unroll
    for (int j = 0; j < 4; ++j) o[j] = (short)f2bf(f[j]);
    *(short4v*)(Xb + i) = o;
  } else {
    const int bx = bid - 8192;                 // [0,768)
    const int w = bx >> 8, rem = bx & 255;
    const int k0 = (rem & 15) * 64, n0 = (rem >> 4) * 64;
    const float* W = (w == 0) ? Wq : ((w == 1) ? Wk : Wv);
    u16* Wo = Wt + (size_t)w * EE * AA;
    const int tx = threadIdx.x & 63, ty = threadIdx.x >> 6;
#pragma unroll
    for (int r = 0; r < 16; ++r) {
      int k = r * 4 + ty;
      t[k][tx] = W[(size_t)(k0 + k) * AA + n0 + tx];
    }
    __syncthreads();
#pragma unroll
    for (int r = 0; r < 16; ++r) {
      int n = r * 4 + ty;
      Wo[(size_t)(n0 + n) * EE + k0 + tx] = f2bf(t[tx][n]);
    }
  }
}

// ---------- P = exp(Q @ K^T / 32) causal, + rowsum (LDS-combined, 128 atomics/block) ----------
__global__ __launch_bounds__(256) void k_scores(const u16* __restrict__ Q, const u16* __restrict__ K,
                                                u16* __restrict__ Sc, float* __restrict__ rowsum) {
  __shared__ __align__(16) char smem[65536];
  __shared__ float rsh[128];
  const int wg = xcd_swz(blockIdx.x, 544);
  const int b = wg / 136, t = wg % 136;
  int i = (int)((sqrtf(8.f * t + 1.f) - 1.f) * 0.5f);
  while ((i + 1) * (i + 2) / 2 <= t) ++i;
  while (i * (i + 1) / 2 > t) --i;
  const int j = t - i * (i + 1) / 2;
  const u16* Ap = Q + (size_t)b * SS * AA + (size_t)i * 128 * AA;
  const u16* Bp = K + (size_t)b * SS * AA + (size_t)j * 128 * AA;
  u16* Op = Sc + (size_t)b * SS * SS;
  float* rs = rowsum + (size_t)b * SS;
  f32x4 acc[4][4];
#pragma unroll
  for (int p = 0; p < 4; ++p)
#pragma unroll
    for (int q = 0; q < 4; ++q) acc[p][q] = (f32x4)0.f;
  if (threadIdx.x < 128) rsh[threadIdx.x] = 0.f;
  gemm_tile(Ap, AA, Bp, AA, AA / 64, smem, acc);   // ends with __syncthreads -> rsh visible
  const int lane = threadIdx.x & 63, wid = threadIdx.x >> 6;
  const int r0 = i * 128 + (wid >> 1) * 64, c0 = j * 128 + (wid & 1) * 64;
#pragma unroll
  for (int mi = 0; mi < 4; ++mi)
#pragma unroll
    for (int r = 0; r < 4; ++r) {
      const int row = r0 + mi * 16 + ((lane >> 4) << 2) + r;
      float psum = 0.f;
#pragma unroll
      for (int ni = 0; ni < 4; ++ni) {
        const int col = c0 + ni * 16 + (lane & 15);
        float e = (col <= row) ? __expf(acc[mi][ni][r] * 0.03125f) : 0.f;
        psum += e;
        Op[(size_t)row * SS + col] = f2bf(e);
      }
      psum += __shfl_xor(psum, 1, 16);
      psum += __shfl_xor(psum, 2, 16);
      psum += __shfl_xor(psum, 4, 16);
      psum += __shfl_xor(psum, 8, 16);
      if ((lane & 15) == 0) atomicAdd(&rsh[row - i * 128], psum);
    }
  __syncthreads();
  if (threadIdx.x < 128) atomicAdd(&rs[i * 128 + threadIdx.x], rsh[threadIdx.x]);
}

// ---------- out = (P @ Vt^T) / rowsum (causal K-loop), fp32 out ----------
// Co-residency pairing (r11): CU c hosts lin=c and lin=c+256 -> i pair {x, 15-x}, 17 units/CU.
__global__ __launch_bounds__(256) void k_pv(const u16* __restrict__ Sc, const u16* __restrict__ Vt,
                                            const float* __restrict__ rowsum, float* __restrict__ Out) {
  __shared__ __align__(16) char smem[65536];
  const int lin = blockIdx.x;          // 512; lin&7 = XCD
  const int x = lin & 7;
  const int half = (lin >> 8) & 1;     // co-resident partner has half^1
  const int rest = (lin >> 3) & 31;    // [0,32): b*8 + nt
  const int b = rest >> 3, nt = rest & 7;
  const int i = half ? (15 - x) : x;
  const u16* Ap = Sc + (size_t)b * SS * SS + (size_t)i * 128 * SS;
  const u16* Bp = Vt + (size_t)b * AA * SS + (size_t)nt * 128 * SS;
  const float* rs = rowsum + (size_t)b * SS;
  float* Op = Out + (size_t)b * SS * AA;
  const int lane = threadIdx.x & 63, wid = threadIdx.x >> 6;
  const int r0 = i * 128 + (wid >> 1) * 64, c0 = nt * 128 + (wid & 1) * 64;
  // hoist rowsum loads above the GEMM (ready since k_scores; latency hides under staging)
  float rsv[4][4];
#pragma unroll
  for (int mi = 0; mi < 4; ++mi)
#pragma unroll
    for (int r = 0; r < 4; ++r)
      rsv[mi][r] = rs[r0 + mi * 16 + ((lane >> 4) << 2) + r];
  f32x4 acc[4][4];
#pragma unroll
  for (int p = 0; p < 4; ++p)
#pragma unroll
    for (int q = 0; q < 4; ++q) acc[p][q] = (f32x4)0.f;
  gemm_tile(Ap, SS, Bp, SS, 2 * (i + 1), smem, acc);
#pragma unroll
  for (int mi = 0; mi < 4; ++mi)
#pragma unroll
    for (int r = 0; r < 4; ++r) {
      const int row = r0 + mi * 16 + ((lane >> 4) << 2) + r;
      const float inv = 1.f / rsv[mi][r];
#pragma unroll
      for (int ni = 0; ni < 4; ++ni) {
        const int col = c0 + ni * 16 + (lane & 15);
        Op[(size_t)row * AA + col] = acc[mi][ni][r] * inv;
      }
    }
}

extern "C" void kernel_launch(void* const* d_in, const int* in_sizes, int n_in,
                              void* d_out, int out_size, void* d_ws, size_t ws_size,
                              hipStream_t stream) {
  const float* X  = (const float*)d_in[0];
  const float* Wq = (const float*)d_in[1];
  const float* Wk = (const float*)d_in[2];
  const float* Wv = (const float*)d_in[3];
  float* Out = (float*)d_out;
  char* ws = (char*)d_ws;
  u16* Xb = (u16*)ws;                              // 16 MiB: [8192][1024]
  u16* Wt = (u16*)(ws + (16u << 20));              // 6 MiB: [3072][1024] (n-major, Q|K|V)
  u16* Qb = (u16*)(ws + (22u << 20));              // 16 MiB  } Qb, Kb contiguous (16MiB apart)
  u16* Kb = (u16*)(ws + (38u << 20));              // 16 MiB  }
  u16* Vt = (u16*)(ws + (70u << 20));              // 16 MiB: per-batch [1024][2048]
  u16* Sc = (u16*)(ws + (86u << 20));              // 32 MiB: [4][2048][2048]
  float* rowsum = (float*)(ws + (118u << 20));     // 32 KiB: [4][2048]

  k_prep<<<dim3(8192 + 768), 256, 0, stream>>>(X, Wq, Wk, Wv, Xb, Wt, rowsum);
  k_proj8<<<dim3(1536), 256, 0, stream>>>(Xb, Wt, Qb, Vt);
  k_scores<<<dim3(136 * BB), 256, 0, stream>>>(Qb, Kb, Sc, rowsum);
  k_pv<<<dim3(512), 256, 0, stream>>>(Sc, Vt, rowsum, Out);
}

// Round 14
// 139.739 us; speedup vs baseline: 1.0499x; 1.0407x over previous
//
#include <hip/hip_runtime.h>
#include <hip/hip_bf16.h>

#define DI __device__ __forceinline__

typedef __attribute__((ext_vector_type(8))) __bf16 bf16x8;
typedef __attribute__((ext_vector_type(4))) float f32x4;
typedef __attribute__((ext_vector_type(8))) short short8;
typedef __attribute__((ext_vector_type(4))) short short4v;
typedef unsigned short u16;

static constexpr int BB = 4, SS = 2048, EE = 1024, AA = 1024;

DI float bf2f(u16 u) { unsigned v = ((unsigned)u) << 16; float f; __builtin_memcpy(&f, &v, 4); return f; }
DI u16 f2bf(float f) { __hip_bfloat16 h = __float2bfloat16(f); u16 u; __builtin_memcpy(&u, &h, 2); return u; }

DI void gload16(const void* g, void* l) {
  __builtin_amdgcn_global_load_lds((const __attribute__((address_space(1))) void*)g,
                                   (__attribute__((address_space(3))) void*)l, 16, 0, 0);
}

// bijective XCD swizzle: nwg % 8 == 0.
DI int xcd_swz(int lin, int nwg) {
  int cpx = nwg >> 3;
  return (lin & 7) * cpx + (lin >> 3);
}

// LDS tile rows are 128B (64 bf16). Physical 16B chunk = logical ^ (row&7).
DI bf16x8 read_frag(const char* lds, int R, int c) {
  return *(const bf16x8*)(lds + R * 128 + ((c ^ (R & 7)) << 4));
}

// ================= 128x128 GEMM core: T3-min double-buffered, 64KB -> 2 blocks/CU ==========
// Key lesson (r9/r10): 2 blocks/CU co-residency (foreign waves fill barrier stalls) beats
// every 1-block/CU software pipeline tried in r3-r9 (680-755 TF there; this class ~805+).
DI void stage_tile(const u16* g, int ld, char* lds, int wid, int lane) {
#pragma unroll
  for (int i = 0; i < 4; ++i) {
    int blk = i * 4 + wid;
    int r = blk * 8 + (lane >> 3);
    int c = (lane & 7) ^ (r & 7);
    gload16((const char*)(g + (size_t)r * ld) + c * 16, lds + blk * 1024);
  }
}

DI void gemm_tile(const u16* Ap, int lda, const u16* Bp, int ldb, int ksteps,
                  char* smem, f32x4 acc[4][4]) {
  const int tid = threadIdx.x, lane = tid & 63, wid = tid >> 6;
  const int wr = wid >> 1, wc = wid & 1;
  stage_tile(Ap, lda, smem, wid, lane);
  stage_tile(Bp, ldb, smem + 16384, wid, lane);
  asm volatile("s_waitcnt vmcnt(0)" ::: "memory");
  __syncthreads();
#pragma unroll 1
  for (int ks = 0; ks < ksteps; ++ks) {
    const char* As = smem + (ks & 1) * 32768;
    const char* Bs = As + 16384;
    char* nxt = smem + ((ks & 1) ^ 1) * 32768;
    if (ks + 1 < ksteps) {
      stage_tile(Ap + (size_t)(ks + 1) * 64, lda, nxt, wid, lane);
      stage_tile(Bp + (size_t)(ks + 1) * 64, ldb, nxt + 16384, wid, lane);
    }
#pragma unroll
    for (int ksub = 0; ksub < 2; ++ksub) {
      const int c = ksub * 4 + (lane >> 4);
      bf16x8 af[4], bfr[4];
#pragma unroll
      for (int mi = 0; mi < 4; ++mi) af[mi] = read_frag(As, wr * 64 + mi * 16 + (lane & 15), c);
#pragma unroll
      for (int ni = 0; ni < 4; ++ni) bfr[ni] = read_frag(Bs, wc * 64 + ni * 16 + (lane & 15), c);
#pragma unroll
      for (int mi = 0; mi < 4; ++mi)
#pragma unroll
        for (int ni = 0; ni < 4; ++ni)
          acc[mi][ni] = __builtin_amdgcn_mfma_f32_16x16x32_bf16(af[mi], bfr[ni], acc[mi][ni], 0, 0, 0);
    }
    if (ks + 1 < ksteps) asm volatile("s_waitcnt vmcnt(0)" ::: "memory");
    __syncthreads();
  }
}

// ================= proj: C[8192][3072] = Xb @ Wt^T via 128^2 tiles =================
// 1536 wgs = 3 exact rounds at 2 blocks/CU. Per-XCD: 8 m-tiles x (12+12 split) n-tiles,
// m-fastest -> L2 working set ~3.3MB < 4MB. Tile is wholly Q, K, or V; V written transposed.
__global__ __launch_bounds__(256) void k_proj8(const u16* __restrict__ Xb, const u16* __restrict__ Wt,
                                               u16* __restrict__ Qb, u16* __restrict__ Vt) {
  __shared__ __align__(16) char smem[65536];
  const int lin = blockIdx.x;            // 1536; lin&7 = XCD
  const int x = lin & 7;
  const int jj = lin >> 3;               // [0,192)
  const int nh = jj / 96, rem = jj - nh * 96;
  const int nt = nh * 12 + (rem >> 3);   // [0,24)
  const int mt = x * 8 + (rem & 7);      // [0,64): 8 m-tiles per XCD
  const u16* Ap = Xb + (size_t)mt * 128 * EE;
  const u16* Bp = Wt + (size_t)nt * 128 * EE;
  f32x4 acc[4][4];
#pragma unroll
  for (int p = 0; p < 4; ++p)
#pragma unroll
    for (int q = 0; q < 4; ++q) acc[p][q] = (f32x4)0.f;
  gemm_tile(Ap, EE, Bp, EE, EE / 64, smem, acc);

  const int lane = threadIdx.x & 63, wid = threadIdx.x >> 6;
  const int lane15 = lane & 15, lhi = lane >> 4;
  const int wr = wid >> 1, wc = wid & 1;
  const int r0 = mt * 128 + wr * 64;
  const int c0 = nt * 128 + wc * 64;
  if (nt < 16) {                         // Q (nt<8) or K (8<=nt<16), row-major
    u16* base = Qb + (size_t)(nt >> 3) * ((size_t)BB * SS * AA);
    const int cc = c0 & 1023;
#pragma unroll
    for (int mi = 0; mi < 4; ++mi)
#pragma unroll
      for (int ni = 0; ni < 4; ++ni)
#pragma unroll
        for (int r = 0; r < 4; ++r) {
          int row = r0 + mi * 16 + lhi * 4 + r;
          base[(size_t)row * AA + cc + ni * 16 + lane15] = f2bf(acc[mi][ni][r]);
        }
  } else {                               // V: write transposed to Vt[b][a][s]
#pragma unroll
    for (int mi = 0; mi < 4; ++mi) {
      const int grow = r0 + mi * 16 + lhi * 4;   // 4 consecutive s-rows
      const int b = grow >> 11, s = grow & 2047;
#pragma unroll
      for (int ni = 0; ni < 4; ++ni) {
        const int a = c0 - 2048 + ni * 16 + lane15;
        short4v o;
#pragma unroll
        for (int r = 0; r < 4; ++r) o[r] = (short)f2bf(acc[mi][ni][r]);
        *(short4v*)(Vt + (size_t)b * AA * SS + (size_t)a * SS + s) = o;
      }
    }
  }
}

// ---------- prep: cast X -> bf16 (16B/thread), cast+transpose W -> Wt, zero rowsum ----------
__global__ __launch_bounds__(256) void k_prep(const float* __restrict__ X, const float* __restrict__ Wq,
                                              const float* __restrict__ Wk, const float* __restrict__ Wv,
                                              u16* __restrict__ Xb, u16* __restrict__ Wt,
                                              float* __restrict__ rowsum) {
  __shared__ float t[64][65];
  const int bid = blockIdx.x;
  if (bid < 8192) {
    if (bid < 32) rowsum[bid * 256 + threadIdx.x] = 0.f;
    size_t i = ((size_t)bid * 256 + threadIdx.x) * 4;
    f32x4 f = *(const f32x4*)(X + i);
    short4v o;
#pragma unroll
    for (int j = 0; j < 4; ++j) o[j] = (short)f2bf(f[j]);
    *(short4v*)(Xb + i) = o;
  } else {
    const int bx = bid - 8192;                 // [0,768)
    const int w = bx >> 8, rem = bx & 255;
    const int k0 = (rem & 15) * 64, n0 = (rem >> 4) * 64;
    const float* W = (w == 0) ? Wq : ((w == 1) ? Wk : Wv);
    u16* Wo = Wt + (size_t)w * EE * AA;
    const int tx = threadIdx.x & 63, ty = threadIdx.x >> 6;
#pragma unroll
    for (int r = 0; r < 16; ++r) {
      int k = r * 4 + ty;
      t[k][tx] = W[(size_t)(k0 + k) * AA + n0 + tx];
    }
    __syncthreads();
#pragma unroll
    for (int r = 0; r < 16; ++r) {
      int n = r * 4 + ty;
      Wo[(size_t)(n0 + n) * EE + k0 + tx] = f2bf(t[tx][n]);
    }
  }
}

// ---------- P = exp(Q @ K^T / 32) causal, + rowsum atomics (r11 version) ----------
__global__ __launch_bounds__(256) void k_scores(const u16* __restrict__ Q, const u16* __restrict__ K,
                                                u16* __restrict__ Sc, float* __restrict__ rowsum) {
  __shared__ __align__(16) char smem[65536];
  const int wg = xcd_swz(blockIdx.x, 544);
  const int b = wg / 136, t = wg % 136;
  int i = (int)((sqrtf(8.f * t + 1.f) - 1.f) * 0.5f);
  while ((i + 1) * (i + 2) / 2 <= t) ++i;
  while (i * (i + 1) / 2 > t) --i;
  const int j = t - i * (i + 1) / 2;
  const u16* Ap = Q + (size_t)b * SS * AA + (size_t)i * 128 * AA;
  const u16* Bp = K + (size_t)b * SS * AA + (size_t)j * 128 * AA;
  u16* Op = Sc + (size_t)b * SS * SS;
  float* rs = rowsum + (size_t)b * SS;
  f32x4 acc[4][4];
#pragma unroll
  for (int p = 0; p < 4; ++p)
#pragma unroll
    for (int q = 0; q < 4; ++q) acc[p][q] = (f32x4)0.f;
  gemm_tile(Ap, AA, Bp, AA, AA / 64, smem, acc);
  const int lane = threadIdx.x & 63, wid = threadIdx.x >> 6;
  const int r0 = i * 128 + (wid >> 1) * 64, c0 = j * 128 + (wid & 1) * 64;
#pragma unroll
  for (int mi = 0; mi < 4; ++mi)
#pragma unroll
    for (int r = 0; r < 4; ++r) {
      const int row = r0 + mi * 16 + ((lane >> 4) << 2) + r;
      float psum = 0.f;
#pragma unroll
      for (int ni = 0; ni < 4; ++ni) {
        const int col = c0 + ni * 16 + (lane & 15);
        float e = (col <= row) ? __expf(acc[mi][ni][r] * 0.03125f) : 0.f;
        psum += e;
        Op[(size_t)row * SS + col] = f2bf(e);
      }
      psum += __shfl_xor(psum, 1, 16);
      psum += __shfl_xor(psum, 2, 16);
      psum += __shfl_xor(psum, 4, 16);
      psum += __shfl_xor(psum, 8, 16);
      if ((lane & 15) == 0) atomicAdd(&rs[row], psum);
    }
}

// ---------- out = (P @ Vt^T) / rowsum (causal K-loop), fp32 out ----------
// Co-residency pairing (r11): CU c hosts lin=c and lin=c+256 -> i pair {x, 15-x}, 17 units/CU.
__global__ __launch_bounds__(256) void k_pv(const u16* __restrict__ Sc, const u16* __restrict__ Vt,
                                            const float* __restrict__ rowsum, float* __restrict__ Out) {
  __shared__ __align__(16) char smem[65536];
  const int lin = blockIdx.x;          // 512; lin&7 = XCD
  const int x = lin & 7;
  const int half = (lin >> 8) & 1;     // co-resident partner has half^1
  const int rest = (lin >> 3) & 31;    // [0,32): b*8 + nt
  const int b = rest >> 3, nt = rest & 7;
  const int i = half ? (15 - x) : x;
  const u16* Ap = Sc + (size_t)b * SS * SS + (size_t)i * 128 * SS;
  const u16* Bp = Vt + (size_t)b * AA * SS + (size_t)nt * 128 * SS;
  const float* rs = rowsum + (size_t)b * SS;
  float* Op = Out + (size_t)b * SS * AA;
  f32x4 acc[4][4];
#pragma unroll
  for (int p = 0; p < 4; ++p)
#pragma unroll
    for (int q = 0; q < 4; ++q) acc[p][q] = (f32x4)0.f;
  gemm_tile(Ap, SS, Bp, SS, 2 * (i + 1), smem, acc);
  const int lane = threadIdx.x & 63, wid = threadIdx.x >> 6;
  const int r0 = i * 128 + (wid >> 1) * 64, c0 = nt * 128 + (wid & 1) * 64;
#pragma unroll
  for (int mi = 0; mi < 4; ++mi)
#pragma unroll
    for (int r = 0; r < 4; ++r) {
      const int row = r0 + mi * 16 + ((lane >> 4) << 2) + r;
      const float inv = 1.f / rs[row];
#pragma unroll
      for (int ni = 0; ni < 4; ++ni) {
        const int col = c0 + ni * 16 + (lane & 15);
        Op[(size_t)row * AA + col] = acc[mi][ni][r] * inv;
      }
    }
}

extern "C" void kernel_launch(void* const* d_in, const int* in_sizes, int n_in,
                              void* d_out, int out_size, void* d_ws, size_t ws_size,
                              hipStream_t stream) {
  const float* X  = (const float*)d_in[0];
  const float* Wq = (const float*)d_in[1];
  const float* Wk = (const float*)d_in[2];
  const float* Wv = (const float*)d_in[3];
  float* Out = (float*)d_out;
  char* ws = (char*)d_ws;
  u16* Xb = (u16*)ws;                              // 16 MiB: [8192][1024]
  u16* Wt = (u16*)(ws + (16u << 20));              // 6 MiB: [3072][1024] (n-major, Q|K|V)
  u16* Qb = (u16*)(ws + (22u << 20));              // 16 MiB  } Qb, Kb contiguous (16MiB apart)
  u16* Kb = (u16*)(ws + (38u << 20));              // 16 MiB  }
  u16* Vt = (u16*)(ws + (70u << 20));              // 16 MiB: per-batch [1024][2048]
  u16* Sc = (u16*)(ws + (86u << 20));              // 32 MiB: [4][2048][2048]
  float* rowsum = (float*)(ws + (118u << 20));     // 32 KiB: [4][2048]
  (void)Kb;

  k_prep<<<dim3(8192 + 768), 256, 0, stream>>>(X, Wq, Wk, Wv, Xb, Wt, rowsum);
  k_proj8<<<dim3(1536), 256, 0, stream>>>(Xb, Wt, Qb, Vt);
  k_scores<<<dim3(136 * BB), 256, 0, stream>>>(Qb, Kb, Sc, rowsum);
  k_pv<<<dim3(512), 256, 0, stream>>>(Sc, Vt, rowsum, Out);
}

// Round 15
// 137.269 us; speedup vs baseline: 1.0688x; 1.0180x over previous
//
#include <hip/hip_runtime.h>
#include <hip/hip_bf16.h>

#define DI __device__ __forceinline__

typedef __attribute__((ext_vector_type(8))) __bf16 bf16x8;
typedef __attribute__((ext_vector_type(4))) float f32x4;
typedef __attribute__((ext_vector_type(8))) short short8;
typedef __attribute__((ext_vector_type(4))) short short4v;
typedef unsigned short u16;

static constexpr int BB = 4, SS = 2048, EE = 1024, AA = 1024;

DI float bf2f(u16 u) { unsigned v = ((unsigned)u) << 16; float f; __builtin_memcpy(&f, &v, 4); return f; }
DI u16 f2bf(float f) { __hip_bfloat16 h = __float2bfloat16(f); u16 u; __builtin_memcpy(&u, &h, 2); return u; }

DI void gload16(const void* g, void* l) {
  __builtin_amdgcn_global_load_lds((const __attribute__((address_space(1))) void*)g,
                                   (__attribute__((address_space(3))) void*)l, 16, 0, 0);
}

// bijective XCD swizzle: nwg % 8 == 0.
DI int xcd_swz(int lin, int nwg) {
  int cpx = nwg >> 3;
  return (lin & 7) * cpx + (lin >> 3);
}

// LDS tile rows are 128B (64 bf16). Physical 16B chunk = logical ^ (row&7).
DI bf16x8 read_frag(const char* lds, int R, int c) {
  return *(const bf16x8*)(lds + R * 128 + ((c ^ (R & 7)) << 4));
}

// ================= 128x128 GEMM core: T3-min double-buffered, 64KB -> 2 blocks/CU ==========
// Key lesson (r9/r10): 2 blocks/CU co-residency (foreign waves fill barrier stalls) beats
// every 1-block/CU software pipeline tried in r3-r9 (680-755 TF there; this class ~805+).
DI void stage_tile(const u16* g, int ld, char* lds, int wid, int lane) {
#pragma unroll
  for (int i = 0; i < 4; ++i) {
    int blk = i * 4 + wid;
    int r = blk * 8 + (lane >> 3);
    int c = (lane & 7) ^ (r & 7);
    gload16((const char*)(g + (size_t)r * ld) + c * 16, lds + blk * 1024);
  }
}

// half-width stage: 64 rows (8KB)
DI void stage_tile_h(const u16* g, int ld, char* lds, int wid, int lane) {
#pragma unroll
  for (int i = 0; i < 2; ++i) {
    int blk = i * 4 + wid;              // 0..7
    int r = blk * 8 + (lane >> 3);      // 0..63
    int c = (lane & 7) ^ (r & 7);
    gload16((const char*)(g + (size_t)r * ld) + c * 16, lds + blk * 1024);
  }
}

DI void gemm_tile(const u16* Ap, int lda, const u16* Bp, int ldb, int ksteps,
                  char* smem, f32x4 acc[4][4]) {
  const int tid = threadIdx.x, lane = tid & 63, wid = tid >> 6;
  const int wr = wid >> 1, wc = wid & 1;
  stage_tile(Ap, lda, smem, wid, lane);
  stage_tile(Bp, ldb, smem + 16384, wid, lane);
  asm volatile("s_waitcnt vmcnt(0)" ::: "memory");
  __syncthreads();
#pragma unroll 1
  for (int ks = 0; ks < ksteps; ++ks) {
    const char* As = smem + (ks & 1) * 32768;
    const char* Bs = As + 16384;
    char* nxt = smem + ((ks & 1) ^ 1) * 32768;
    if (ks + 1 < ksteps) {
      stage_tile(Ap + (size_t)(ks + 1) * 64, lda, nxt, wid, lane);
      stage_tile(Bp + (size_t)(ks + 1) * 64, ldb, nxt + 16384, wid, lane);
    }
#pragma unroll
    for (int ksub = 0; ksub < 2; ++ksub) {
      const int c = ksub * 4 + (lane >> 4);
      bf16x8 af[4], bfr[4];
#pragma unroll
      for (int mi = 0; mi < 4; ++mi) af[mi] = read_frag(As, wr * 64 + mi * 16 + (lane & 15), c);
#pragma unroll
      for (int ni = 0; ni < 4; ++ni) bfr[ni] = read_frag(Bs, wc * 64 + ni * 16 + (lane & 15), c);
#pragma unroll
      for (int mi = 0; mi < 4; ++mi)
#pragma unroll
        for (int ni = 0; ni < 4; ++ni)
          acc[mi][ni] = __builtin_amdgcn_mfma_f32_16x16x32_bf16(af[mi], bfr[ni], acc[mi][ni], 0, 0, 0);
    }
    if (ks + 1 < ksteps) asm volatile("s_waitcnt vmcnt(0)" ::: "memory");
    __syncthreads();
  }
}

// ================= proj: C[8192][3072] = Xb @ Wt^T via 128^2 tiles =================
// 1536 wgs = 3 exact rounds at 2 blocks/CU. Per-XCD: 8 m-tiles x (12+12 split) n-tiles,
// m-fastest -> L2 working set ~3.3MB < 4MB. Tile is wholly Q, K, or V; V written transposed.
__global__ __launch_bounds__(256) void k_proj8(const u16* __restrict__ Xb, const u16* __restrict__ Wt,
                                               u16* __restrict__ Qb, u16* __restrict__ Vt) {
  __shared__ __align__(16) char smem[65536];
  const int lin = blockIdx.x;            // 1536; lin&7 = XCD
  const int x = lin & 7;
  const int jj = lin >> 3;               // [0,192)
  const int nh = jj / 96, rem = jj - nh * 96;
  const int nt = nh * 12 + (rem >> 3);   // [0,24)
  const int mt = x * 8 + (rem & 7);      // [0,64): 8 m-tiles per XCD
  const u16* Ap = Xb + (size_t)mt * 128 * EE;
  const u16* Bp = Wt + (size_t)nt * 128 * EE;
  f32x4 acc[4][4];
#pragma unroll
  for (int p = 0; p < 4; ++p)
#pragma unroll
    for (int q = 0; q < 4; ++q) acc[p][q] = (f32x4)0.f;
  gemm_tile(Ap, EE, Bp, EE, EE / 64, smem, acc);

  const int lane = threadIdx.x & 63, wid = threadIdx.x >> 6;
  const int lane15 = lane & 15, lhi = lane >> 4;
  const int wr = wid >> 1, wc = wid & 1;
  const int r0 = mt * 128 + wr * 64;
  const int c0 = nt * 128 + wc * 64;
  if (nt < 16) {                         // Q (nt<8) or K (8<=nt<16), row-major
    u16* base = Qb + (size_t)(nt >> 3) * ((size_t)BB * SS * AA);
    const int cc = c0 & 1023;
#pragma unroll
    for (int mi = 0; mi < 4; ++mi)
#pragma unroll
      for (int ni = 0; ni < 4; ++ni)
#pragma unroll
        for (int r = 0; r < 4; ++r) {
          int row = r0 + mi * 16 + lhi * 4 + r;
          base[(size_t)row * AA + cc + ni * 16 + lane15] = f2bf(acc[mi][ni][r]);
        }
  } else {                               // V: write transposed to Vt[b][a][s]
#pragma unroll
    for (int mi = 0; mi < 4; ++mi) {
      const int grow = r0 + mi * 16 + lhi * 4;   // 4 consecutive s-rows
      const int b = grow >> 11, s = grow & 2047;
#pragma unroll
      for (int ni = 0; ni < 4; ++ni) {
        const int a = c0 - 2048 + ni * 16 + lane15;
        short4v o;
#pragma unroll
        for (int r = 0; r < 4; ++r) o[r] = (short)f2bf(acc[mi][ni][r]);
        *(short4v*)(Vt + (size_t)b * AA * SS + (size_t)a * SS + s) = o;
      }
    }
  }
}

// ---------- prep: cast X -> bf16 (16B/thread), cast+transpose W -> Wt, zero rowsum ----------
__global__ __launch_bounds__(256) void k_prep(const float* __restrict__ X, const float* __restrict__ Wq,
                                              const float* __restrict__ Wk, const float* __restrict__ Wv,
                                              u16* __restrict__ Xb, u16* __restrict__ Wt,
                                              float* __restrict__ rowsum) {
  __shared__ float t[64][65];
  const int bid = blockIdx.x;
  if (bid < 8192) {
    if (bid < 32) rowsum[bid * 256 + threadIdx.x] = 0.f;
    size_t i = ((size_t)bid * 256 + threadIdx.x) * 4;
    f32x4 f = *(const f32x4*)(X + i);
    short4v o;
#pragma unroll
    for (int j = 0; j < 4; ++j) o[j] = (short)f2bf(f[j]);
    *(short4v*)(Xb + i) = o;
  } else {
    const int bx = bid - 8192;                 // [0,768)
    const int w = bx >> 8, rem = bx & 255;
    const int k0 = (rem & 15) * 64, n0 = (rem >> 4) * 64;
    const float* W = (w == 0) ? Wq : ((w == 1) ? Wk : Wv);
    u16* Wo = Wt + (size_t)w * EE * AA;
    const int tx = threadIdx.x & 63, ty = threadIdx.x >> 6;
#pragma unroll
    for (int r = 0; r < 16; ++r) {
      int k = r * 4 + ty;
      t[k][tx] = W[(size_t)(k0 + k) * AA + n0 + tx];
    }
    __syncthreads();
#pragma unroll
    for (int r = 0; r < 16; ++r) {
      int n = r * 4 + ty;
      Wo[(size_t)(n0 + n) * EE + k0 + tx] = f2bf(t[tx][n]);
    }
  }
}

// ---------- P = exp(Q @ K^T / 32) causal, + rowsum atomics ----------
// Tail fix (r15): 544 tiles over 512 co-resident slots left a 32-tile second round (~14us
// for 6% of the work). Blocks 0-511 = full tiles (round 1); blocks 512-575 = 64 column-half
// tiles (128x64, ~0.55x time) of the last 32 swizzle positions -> they backfill as slots
// free; makespan ~1.55 rounds instead of 2.
__global__ __launch_bounds__(256) void k_scores(const u16* __restrict__ Q, const u16* __restrict__ K,
                                                u16* __restrict__ Sc, float* __restrict__ rowsum) {
  __shared__ __align__(16) char smem[65536];
  const int lin = blockIdx.x;            // 576
  int p, half;
  if (lin < 512) { p = lin; half = -1; }
  else { int e = lin - 512; p = 512 + (e >> 1); half = e & 1; }
  const int wg = xcd_swz(p, 544);
  const int b = wg / 136, t = wg % 136;
  int i = (int)((sqrtf(8.f * t + 1.f) - 1.f) * 0.5f);
  while ((i + 1) * (i + 2) / 2 <= t) ++i;
  while (i * (i + 1) / 2 > t) --i;
  const int j = t - i * (i + 1) / 2;
  u16* Op = Sc + (size_t)b * SS * SS;
  float* rs = rowsum + (size_t)b * SS;
  const int lane = threadIdx.x & 63, wid = threadIdx.x >> 6;
  const int lane15 = lane & 15, lhi = lane >> 4;

  if (half < 0) {
    // ---- full 128x128 tile ----
    const u16* Ap = Q + (size_t)b * SS * AA + (size_t)i * 128 * AA;
    const u16* Bp = K + (size_t)b * SS * AA + (size_t)j * 128 * AA;
    f32x4 acc[4][4];
#pragma unroll
    for (int pp = 0; pp < 4; ++pp)
#pragma unroll
      for (int qq = 0; qq < 4; ++qq) acc[pp][qq] = (f32x4)0.f;
    gemm_tile(Ap, AA, Bp, AA, AA / 64, smem, acc);
    const int r0 = i * 128 + (wid >> 1) * 64, c0 = j * 128 + (wid & 1) * 64;
#pragma unroll
    for (int mi = 0; mi < 4; ++mi)
#pragma unroll
      for (int r = 0; r < 4; ++r) {
        const int row = r0 + mi * 16 + lhi * 4 + r;
        float psum = 0.f;
#pragma unroll
        for (int ni = 0; ni < 4; ++ni) {
          const int col = c0 + ni * 16 + lane15;
          float e = (col <= row) ? __expf(acc[mi][ni][r] * 0.03125f) : 0.f;
          psum += e;
          Op[(size_t)row * SS + col] = f2bf(e);
        }
        psum += __shfl_xor(psum, 1, 16);
        psum += __shfl_xor(psum, 2, 16);
        psum += __shfl_xor(psum, 4, 16);
        psum += __shfl_xor(psum, 8, 16);
        if (lane15 == 0) atomicAdd(&rs[row], psum);
      }
  } else {
    // ---- half tile: rows i*128..+128, cols j*128 + half*64 .. +64 ----
    const u16* Ap = Q + (size_t)b * SS * AA + (size_t)i * 128 * AA;
    const u16* Bp = K + (size_t)b * SS * AA + (size_t)(j * 128 + half * 64) * AA;
    f32x4 acc[2][4];
#pragma unroll
    for (int pp = 0; pp < 2; ++pp)
#pragma unroll
      for (int qq = 0; qq < 4; ++qq) acc[pp][qq] = (f32x4)0.f;
    // 4 waves x (32 rows x 64 cols). A: 16KB stage; B: 8KB stage. Same dbuf layout.
    stage_tile(Ap, AA, smem, wid, lane);
    stage_tile_h(Bp, AA, smem + 16384, wid, lane);
    asm volatile("s_waitcnt vmcnt(0)" ::: "memory");
    __syncthreads();
#pragma unroll 1
    for (int ks = 0; ks < 16; ++ks) {
      const char* As = smem + (ks & 1) * 32768;
      const char* Bs = As + 16384;
      char* nxt = smem + ((ks & 1) ^ 1) * 32768;
      if (ks + 1 < 16) {
        stage_tile(Ap + (size_t)(ks + 1) * 64, AA, nxt, wid, lane);
        stage_tile_h(Bp + (size_t)(ks + 1) * 64, AA, nxt + 16384, wid, lane);
      }
#pragma unroll
      for (int ksub = 0; ksub < 2; ++ksub) {
        const int c = ksub * 4 + lhi;
        bf16x8 af[2], bfr[4];
#pragma unroll
        for (int mi = 0; mi < 2; ++mi) af[mi] = read_frag(As, wid * 32 + mi * 16 + lane15, c);
#pragma unroll
        for (int ni = 0; ni < 4; ++ni) bfr[ni] = read_frag(Bs, ni * 16 + lane15, c);
#pragma unroll
        for (int mi = 0; mi < 2; ++mi)
#pragma unroll
          for (int ni = 0; ni < 4; ++ni)
            acc[mi][ni] = __builtin_amdgcn_mfma_f32_16x16x32_bf16(af[mi], bfr[ni], acc[mi][ni], 0, 0, 0);
      }
      if (ks + 1 < 16) asm volatile("s_waitcnt vmcnt(0)" ::: "memory");
      __syncthreads();
    }
    const int c0h = j * 128 + half * 64;
#pragma unroll
    for (int mi = 0; mi < 2; ++mi)
#pragma unroll
      for (int r = 0; r < 4; ++r) {
        const int row = i * 128 + wid * 32 + mi * 16 + lhi * 4 + r;
        float psum = 0.f;
#pragma unroll
        for (int ni = 0; ni < 4; ++ni) {
          const int col = c0h + ni * 16 + lane15;
          float e = (col <= row) ? __expf(acc[mi][ni][r] * 0.03125f) : 0.f;
          psum += e;
          Op[(size_t)row * SS + col] = f2bf(e);
        }
        psum += __shfl_xor(psum, 1, 16);
        psum += __shfl_xor(psum, 2, 16);
        psum += __shfl_xor(psum, 4, 16);
        psum += __shfl_xor(psum, 8, 16);
        if (lane15 == 0) atomicAdd(&rs[row], psum);
      }
  }
}

// ---------- out = (P @ Vt^T) / rowsum (causal K-loop), fp32 out ----------
// Co-residency pairing (r11): CU c hosts lin=c and lin=c+256 -> i pair {x, 15-x}, 17 units/CU.
__global__ __launch_bounds__(256) void k_pv(const u16* __restrict__ Sc, const u16* __restrict__ Vt,
                                            const float* __restrict__ rowsum, float* __restrict__ Out) {
  __shared__ __align__(16) char smem[65536];
  const int lin = blockIdx.x;          // 512; lin&7 = XCD
  const int x = lin & 7;
  const int half = (lin >> 8) & 1;     // co-resident partner has half^1
  const int rest = (lin >> 3) & 31;    // [0,32): b*8 + nt
  const int b = rest >> 3, nt = rest & 7;
  const int i = half ? (15 - x) : x;
  const u16* Ap = Sc + (size_t)b * SS * SS + (size_t)i * 128 * SS;
  const u16* Bp = Vt + (size_t)b * AA * SS + (size_t)nt * 128 * SS;
  const float* rs = rowsum + (size_t)b * SS;
  float* Op = Out + (size_t)b * SS * AA;
  f32x4 acc[4][4];
#pragma unroll
  for (int p = 0; p < 4; ++p)
#pragma unroll
    for (int q = 0; q < 4; ++q) acc[p][q] = (f32x4)0.f;
  gemm_tile(Ap, SS, Bp, SS, 2 * (i + 1), smem, acc);
  const int lane = threadIdx.x & 63, wid = threadIdx.x >> 6;
  const int r0 = i * 128 + (wid >> 1) * 64, c0 = nt * 128 + (wid & 1) * 64;
#pragma unroll
  for (int mi = 0; mi < 4; ++mi)
#pragma unroll
    for (int r = 0; r < 4; ++r) {
      const int row = r0 + mi * 16 + ((lane >> 4) << 2) + r;
      const float inv = 1.f / rs[row];
#pragma unroll
      for (int ni = 0; ni < 4; ++ni) {
        const int col = c0 + ni * 16 + (lane & 15);
        Op[(size_t)row * AA + col] = acc[mi][ni][r] * inv;
      }
    }
}

extern "C" void kernel_launch(void* const* d_in, const int* in_sizes, int n_in,
                              void* d_out, int out_size, void* d_ws, size_t ws_size,
                              hipStream_t stream) {
  const float* X  = (const float*)d_in[0];
  const float* Wq = (const float*)d_in[1];
  const float* Wk = (const float*)d_in[2];
  const float* Wv = (const float*)d_in[3];
  float* Out = (float*)d_out;
  char* ws = (char*)d_ws;
  u16* Xb = (u16*)ws;                              // 16 MiB: [8192][1024]
  u16* Wt = (u16*)(ws + (16u << 20));              // 6 MiB: [3072][1024] (n-major, Q|K|V)
  u16* Qb = (u16*)(ws + (22u << 20));              // 16 MiB  } Qb, Kb contiguous (16MiB apart)
  u16* Kb = (u16*)(ws + (38u << 20));              // 16 MiB  }
  u16* Vt = (u16*)(ws + (70u << 20));              // 16 MiB: per-batch [1024][2048]
  u16* Sc = (u16*)(ws + (86u << 20));              // 32 MiB: [4][2048][2048]
  float* rowsum = (float*)(ws + (118u << 20));     // 32 KiB: [4][2048]
  (void)Kb;

  k_prep<<<dim3(8192 + 768), 256, 0, stream>>>(X, Wq, Wk, Wv, Xb, Wt, rowsum);
  k_proj8<<<dim3(1536), 256, 0, stream>>>(Xb, Wt, Qb, Vt);
  k_scores<<<dim3(576), 256, 0, stream>>>(Qb, Kb, Sc, rowsum);
  k_pv<<<dim3(512), 256, 0, stream>>>(Sc, Vt, rowsum, Out);
}